// Round 7
// baseline (214.864 us; speedup 1.0000x reference)
//
#include <hip/hip_runtime.h>
#include <float.h>

// Problem constants (match reference setup_inputs / make_anchors)
#define B_SZ 256
#define N_ANCH 6300
#define N_CLS 10
#define TOPK_K 5

#define FOCAL_BLOCKS 2048
#define TOTAL_BLOCKS (FOCAL_BLOCKS + B_SZ)   // 2304

// ws layout (first 64 B zeroed each launch):
//   acc[0] = focal sum, acc[1] = box sum, acc[2] = corr sum  (doubles)
//   counter at byte 24 (unsigned int)

// ---------- device helpers ----------

__device__ __forceinline__ void anchor_geom(int a, float& gx, float& gy, float& stride) {
    // level 0: stride 8, 60x80 -> 4800 ; level 1: stride 16, 30x40 -> 1200 ; level 2: stride 32, 15x20 -> 300
    if (a < 4800) {
        stride = 8.0f;
        int x = a % 80, y = a / 80;
        gx = x + 0.5f; gy = y + 0.5f;
    } else if (a < 6000) {
        int r = a - 4800;
        stride = 16.0f;
        int x = r % 40, y = r / 40;
        gx = x + 0.5f; gy = y + 0.5f;
    } else {
        int r = a - 6000;
        stride = 32.0f;
        int x = r % 20, y = r / 20;
        gx = x + 0.5f; gy = y + 0.5f;
    }
}

// focal(t=0) = 0.25 * sigmoid(s)^2 * softplus(s) ; focal(t=1)(s) == focal(t=0)(-s)
// Flat, branch-free, native v_exp_f32 / v_log_f32 / v_rcp_f32 (~14 VALU instrs).
__device__ __forceinline__ float focal0_fast(float s) {
    const float LOG2E = 1.4426950408889634f;
    const float LN2   = 0.6931471805599453f;
    float a   = fabsf(s);
    float u   = __builtin_amdgcn_exp2f(-a * LOG2E);   // e^{-|s|}  in (0,1]
    float opu = 1.0f + u;
    float l   = __builtin_amdgcn_logf(opu) * LN2;     // log1p(e^{-|s|})
    float bce = fmaxf(s, 0.0f) + l;                   // softplus(s)
    float r   = __builtin_amdgcn_rcpf(opu);
    float num = (s >= 0.0f) ? 1.0f : u;
    float sg  = num * r;                              // sigmoid(s)
    return 0.25f * sg * sg * bce;
}

// ---------- single fused kernel ----------
// blocks [0, FOCAL_BLOCKS)          : grid-strided focal(t=0) sum over all scores
// blocks [FOCAL_BLOCKS, +B_SZ)      : per-batch top-5 + giou + focal correction
// every block: atomicAdd(double) partials -> last block finalizes.

__global__ __launch_bounds__(256)
void fused_loss_kernel(const float*  __restrict__ pb,   // (B,4,6300)
                       const float*  __restrict__ ps,   // (B,10,6300)
                       const float*  __restrict__ tb,   // (B,4) cxcywh
                       const int*    __restrict__ tc,   // (B,)
                       double* __restrict__ acc,        // 3 doubles (zeroed)
                       unsigned int* __restrict__ counter, // zeroed
                       float* __restrict__ out)
{
    const int blk = blockIdx.x;
    const int tid = threadIdx.x;

    double p_focal = 0.0, p_box = 0.0, p_corr = 0.0;

    __shared__ double sacc[256];
    __shared__ unsigned long long wmin[4];
    __shared__ unsigned long long ssel[TOPK_K];
    __shared__ double sbox[TOPK_K], scorr[TOPK_K];

    if (blk < FOCAL_BLOCKS) {
        // ---------- streaming focal over pred_scores ----------
        const float4* ps4 = (const float4*)ps;
        const int n4 = (B_SZ * N_CLS * N_ANCH) / 4;       // 4,032,000
        const int stride = FOCAL_BLOCKS * 256;
        double a = 0.0;
        for (int i = blk * 256 + tid; i < n4; i += stride) {
            float4 v = ps4[i];
            float fs = focal0_fast(v.x) + focal0_fast(v.y)
                     + focal0_fast(v.z) + focal0_fast(v.w);
            a += (double)fs;
        }
        sacc[tid] = a;
        __syncthreads();
        for (int s = 128; s > 0; s >>= 1) {
            if (tid < s) sacc[tid] += sacc[tid + s];
            __syncthreads();
        }
        p_focal = sacc[0];
    } else {
        // ---------- per-batch top-5 + box loss + focal correction ----------
        const int b = blk - FOCAL_BLOCKS;
        const float txc = tb[b * 4 + 0];
        const float tyc = tb[b * 4 + 1];

        // per-thread top-5 (ascending); key = (dist_bits<<32)|idx reproduces
        // lax.top_k's value-then-lower-index ordering exactly.
        unsigned long long best[TOPK_K];
        #pragma unroll
        for (int k = 0; k < TOPK_K; ++k) best[k] = ~0ull;

        for (int a = tid; a < N_ANCH; a += 256) {
            float gx, gy, st;
            anchor_geom(a, gx, gy, st);
            // match reference rounding: mul, sub, mul, mul, add, sqrt (no fma)
            float dx = __fsub_rn(__fmul_rn(gx, st), txc);
            float dy = __fsub_rn(__fmul_rn(gy, st), tyc);
            float d2 = __fadd_rn(__fmul_rn(dx, dx), __fmul_rn(dy, dy));
            float d  = sqrtf(d2);
            unsigned long long key =
                ((unsigned long long)__float_as_uint(d) << 32) | (unsigned int)a;
            if (key < best[TOPK_K - 1]) {
                best[TOPK_K - 1] = key;
                #pragma unroll
                for (int k = TOPK_K - 1; k > 0; --k) {
                    unsigned long long lo = best[k - 1], hi = best[k];
                    bool sw = hi < lo;
                    best[k - 1] = sw ? hi : lo;
                    best[k]     = sw ? lo : hi;
                }
            }
        }

        // block merge: 5 rounds of (wave shuffle-min -> 4-entry LDS -> pick)
        int ptr = 0;
        for (int p = 0; p < TOPK_K; ++p) {
            unsigned long long cand = (ptr < TOPK_K) ? best[ptr] : ~0ull;
            unsigned long long m = cand;
            #pragma unroll
            for (int off = 32; off > 0; off >>= 1) {
                unsigned long long o = __shfl_xor(m, off, 64);
                m = (o < m) ? o : m;
            }
            if ((tid & 63) == 0) wmin[tid >> 6] = m;
            __syncthreads();
            if (tid == 0) {
                unsigned long long m01 = (wmin[0] < wmin[1]) ? wmin[0] : wmin[1];
                unsigned long long m23 = (wmin[2] < wmin[3]) ? wmin[2] : wmin[3];
                ssel[p] = (m01 < m23) ? m01 : m23;
            }
            __syncthreads();
            if (ptr < TOPK_K && cand == ssel[p]) ptr++;  // unique key -> exactly one advances
        }

        // decode + giou + focal correction for the 5 selected anchors
        if (tid < TOPK_K) {
            const int a = (int)(ssel[tid] & 0xffffffffu);
            float gx, gy, st;
            anchor_geom(a, gx, gy, st);

            const int base = b * 4 * N_ANCH + a;
            float ddx = pb[base + 0 * N_ANCH];
            float ddy = pb[base + 1 * N_ANCH];
            float tw  = pb[base + 2 * N_ANCH];
            float th  = pb[base + 3 * N_ANCH];

            float cx = (gx + ddx) * st;
            float cy = (gy + ddy) * st;
            float w  = expf(fminf(tw, 10.0f)) * st;
            float h  = expf(fminf(th, 10.0f)) * st;

            float ax0 = cx - w * 0.5f, ay0 = cy - h * 0.5f;
            float ax1 = cx + w * 0.5f, ay1 = cy + h * 0.5f;

            float gcx = tb[b * 4 + 0], gcy = tb[b * 4 + 1];
            float gw  = tb[b * 4 + 2], gh  = tb[b * 4 + 3];
            float bx0 = gcx - gw * 0.5f, by0 = gcy - gh * 0.5f;
            float bx1 = gcx + gw * 0.5f, by1 = gcy + gh * 0.5f;

            float ltx = fmaxf(ax0, bx0), lty = fmaxf(ay0, by0);
            float rbx = fminf(ax1, bx1), rby = fminf(ay1, by1);
            float iw = fmaxf(rbx - ltx, 0.0f), ih = fmaxf(rby - lty, 0.0f);
            float inter = iw * ih;
            float areaA = (ax1 - ax0) * (ay1 - ay0);
            float areaB = (bx1 - bx0) * (by1 - by0);
            float uni = areaA + areaB - inter;
            float iou = inter / uni;
            float ccx0 = fminf(ax0, bx0), ccy0 = fminf(ay0, by0);
            float ccx1 = fmaxf(ax1, bx1), ccy1 = fmaxf(ay1, by1);
            float cw = fmaxf(ccx1 - ccx0, 0.0f), ch = fmaxf(ccy1 - ccy0, 0.0f);
            float areaC = cw * ch;
            float giou = iou - (areaC - uni) / areaC;
            sbox[tid] = (double)(1.0f - giou);

            const int cls = tc[b];
            float s = ps[b * (N_CLS * N_ANCH) + cls * N_ANCH + a];
            scorr[tid] = (double)focal0_fast(-s) - (double)focal0_fast(s);
        }
        __syncthreads();
        if (tid == 0) {
            for (int k = 0; k < TOPK_K; ++k) { p_box += sbox[k]; p_corr += scorr[k]; }
        }
    }

    // ---------- global accumulate + last-block finalize ----------
    if (tid == 0) {
        atomicAdd(&acc[0], p_focal);
        atomicAdd(&acc[1], p_box);
        atomicAdd(&acc[2], p_corr);
        __threadfence();
        unsigned int old = atomicAdd(counter, 1u);
        if (old == (unsigned int)(TOTAL_BLOCKS - 1)) {
            // read coherently via atomic RMW on the same addresses
            double f = atomicAdd(&acc[0], 0.0);
            double bx = atomicAdd(&acc[1], 0.0);
            double cr = atomicAdd(&acc[2], 0.0);
            double loss_cls = (f + cr) / (double)B_SZ;
            double loss_box = bx / (double)(B_SZ * TOPK_K);
            out[0] = (float)(5.0 * loss_box + loss_cls);
            out[1] = (float)loss_box;
            out[2] = (float)loss_cls;
        }
    }
}

// ---------- launch ----------

extern "C" void kernel_launch(void* const* d_in, const int* in_sizes, int n_in,
                              void* d_out, int out_size, void* d_ws, size_t ws_size,
                              hipStream_t stream) {
    const float* pb = (const float*)d_in[0];   // pred_boxes  (256,4,6300)
    const float* ps = (const float*)d_in[1];   // pred_scores (256,10,6300)
    const float* tb = (const float*)d_in[2];   // targets_bbox (256,4)
    const int*   tc = (const int*)d_in[3];     // targets_cls (256,)
    float* out = (float*)d_out;

    double*       acc     = (double*)d_ws;                 // 3 doubles
    unsigned int* counter = (unsigned int*)((char*)d_ws + 24);

    // zero accumulators + counter (graph-capturable memset node)
    hipMemsetAsync(d_ws, 0, 64, stream);

    fused_loss_kernel<<<TOTAL_BLOCKS, 256, 0, stream>>>(pb, ps, tb, tc, acc, counter, out);
}

// Round 8
// 119.583 us; speedup vs baseline: 1.7968x; 1.7968x over previous
//
#include <hip/hip_runtime.h>
#include <float.h>

// Problem constants (match reference setup_inputs / make_anchors)
#define B_SZ 256
#define N_ANCH 6300
#define N_CLS 10
#define TOPK_K 5

#define FOCAL_BLOCKS 2048
#define TOTAL_BLOCKS (FOCAL_BLOCKS + B_SZ)   // 2304

// ws layout (all doubles, every slot written by kernel 1 before kernel 2 reads):
//   [0, 2048)            : per-block focal partials
//   [2048, 2304)         : per-batch box partials
//   [2304, 2560)         : per-batch corr partials

// ---------- device helpers ----------

__device__ __forceinline__ void anchor_geom(int a, float& gx, float& gy, float& stride) {
    // level 0: stride 8, 60x80 -> 4800 ; level 1: stride 16, 30x40 -> 1200 ; level 2: stride 32, 15x20 -> 300
    if (a < 4800) {
        stride = 8.0f;
        int x = a % 80, y = a / 80;
        gx = x + 0.5f; gy = y + 0.5f;
    } else if (a < 6000) {
        int r = a - 4800;
        stride = 16.0f;
        int x = r % 40, y = r / 40;
        gx = x + 0.5f; gy = y + 0.5f;
    } else {
        int r = a - 6000;
        stride = 32.0f;
        int x = r % 20, y = r / 20;
        gx = x + 0.5f; gy = y + 0.5f;
    }
}

// focal(t=0) = 0.25 * sigmoid(s)^2 * softplus(s) ; focal(t=1)(s) == focal(t=0)(-s)
// Flat, branch-free, native v_exp_f32 / v_log_f32 / v_rcp_f32 (~14 VALU instrs).
__device__ __forceinline__ float focal0_fast(float s) {
    const float LOG2E = 1.4426950408889634f;
    const float LN2   = 0.6931471805599453f;
    float a   = fabsf(s);
    float u   = __builtin_amdgcn_exp2f(-a * LOG2E);   // e^{-|s|}  in (0,1]
    float opu = 1.0f + u;
    float l   = __builtin_amdgcn_logf(opu) * LN2;     // log1p(e^{-|s|})
    float bce = fmaxf(s, 0.0f) + l;                   // softplus(s)
    float r   = __builtin_amdgcn_rcpf(opu);
    float num = (s >= 0.0f) ? 1.0f : u;
    float sg  = num * r;                              // sigmoid(s)
    return 0.25f * sg * sg * bce;
}

// ---------- kernel 1: fused work, contention-free partial writes ----------
// blocks [0, FOCAL_BLOCKS)     : grid-strided focal(t=0) sum over all scores
// blocks [FOCAL_BLOCKS, +B_SZ) : per-batch top-5 + giou + focal correction
// Each block writes partials to DISTINCT ws slots (no atomics — round 7 showed
// 9216 same-line device atomics serialize at ~14 ns each = 127 us).

__global__ __launch_bounds__(256)
void fused_work_kernel(const float*  __restrict__ pb,   // (B,4,6300)
                       const float*  __restrict__ ps,   // (B,10,6300)
                       const float*  __restrict__ tb,   // (B,4) cxcywh
                       const int*    __restrict__ tc,   // (B,)
                       double* __restrict__ part)       // 2560 doubles
{
    const int blk = blockIdx.x;
    const int tid = threadIdx.x;

    if (blk < FOCAL_BLOCKS) {
        // ---------- streaming focal over pred_scores ----------
        const float4* ps4 = (const float4*)ps;
        const int n4 = (B_SZ * N_CLS * N_ANCH) / 4;       // 4,032,000
        const int stride = FOCAL_BLOCKS * 256;
        double a = 0.0;
        for (int i = blk * 256 + tid; i < n4; i += stride) {
            float4 v = ps4[i];
            float fs = focal0_fast(v.x) + focal0_fast(v.y)
                     + focal0_fast(v.z) + focal0_fast(v.w);
            a += (double)fs;
        }
        __shared__ double sacc[256];
        sacc[tid] = a;
        __syncthreads();
        for (int s = 128; s > 0; s >>= 1) {
            if (tid < s) sacc[tid] += sacc[tid + s];
            __syncthreads();
        }
        if (tid == 0) part[blk] = sacc[0];
    } else {
        // ---------- per-batch top-5 + box loss + focal correction ----------
        const int b = blk - FOCAL_BLOCKS;
        const float txc = tb[b * 4 + 0];
        const float tyc = tb[b * 4 + 1];

        // per-thread top-5 (ascending); key = (dist_bits<<32)|idx reproduces
        // lax.top_k's value-then-lower-index ordering exactly.
        unsigned long long best[TOPK_K];
        #pragma unroll
        for (int k = 0; k < TOPK_K; ++k) best[k] = ~0ull;

        for (int a = tid; a < N_ANCH; a += 256) {
            float gx, gy, st;
            anchor_geom(a, gx, gy, st);
            // match reference rounding: mul, sub, mul, mul, add, sqrt (no fma)
            float dx = __fsub_rn(__fmul_rn(gx, st), txc);
            float dy = __fsub_rn(__fmul_rn(gy, st), tyc);
            float d2 = __fadd_rn(__fmul_rn(dx, dx), __fmul_rn(dy, dy));
            float d  = sqrtf(d2);
            unsigned long long key =
                ((unsigned long long)__float_as_uint(d) << 32) | (unsigned int)a;
            if (key < best[TOPK_K - 1]) {
                best[TOPK_K - 1] = key;
                #pragma unroll
                for (int k = TOPK_K - 1; k > 0; --k) {
                    unsigned long long lo = best[k - 1], hi = best[k];
                    bool sw = hi < lo;
                    best[k - 1] = sw ? hi : lo;
                    best[k]     = sw ? lo : hi;
                }
            }
        }

        // block merge: 5 rounds of (wave shuffle-min -> 4-entry LDS -> pick)
        __shared__ unsigned long long wmin[4];
        __shared__ unsigned long long ssel[TOPK_K];
        int ptr = 0;
        for (int p = 0; p < TOPK_K; ++p) {
            unsigned long long cand = (ptr < TOPK_K) ? best[ptr] : ~0ull;
            unsigned long long m = cand;
            #pragma unroll
            for (int off = 32; off > 0; off >>= 1) {
                unsigned long long o = __shfl_xor(m, off, 64);
                m = (o < m) ? o : m;
            }
            if ((tid & 63) == 0) wmin[tid >> 6] = m;
            __syncthreads();
            if (tid == 0) {
                unsigned long long m01 = (wmin[0] < wmin[1]) ? wmin[0] : wmin[1];
                unsigned long long m23 = (wmin[2] < wmin[3]) ? wmin[2] : wmin[3];
                ssel[p] = (m01 < m23) ? m01 : m23;
            }
            __syncthreads();
            if (ptr < TOPK_K && cand == ssel[p]) ptr++;  // unique key -> exactly one advances
        }

        // decode + giou + focal correction for the 5 selected anchors
        __shared__ double sbox[TOPK_K], scorr[TOPK_K];
        if (tid < TOPK_K) {
            const int a = (int)(ssel[tid] & 0xffffffffu);
            float gx, gy, st;
            anchor_geom(a, gx, gy, st);

            const int base = b * 4 * N_ANCH + a;
            float ddx = pb[base + 0 * N_ANCH];
            float ddy = pb[base + 1 * N_ANCH];
            float tw  = pb[base + 2 * N_ANCH];
            float th  = pb[base + 3 * N_ANCH];

            float cx = (gx + ddx) * st;
            float cy = (gy + ddy) * st;
            float w  = expf(fminf(tw, 10.0f)) * st;
            float h  = expf(fminf(th, 10.0f)) * st;

            float ax0 = cx - w * 0.5f, ay0 = cy - h * 0.5f;
            float ax1 = cx + w * 0.5f, ay1 = cy + h * 0.5f;

            float gcx = tb[b * 4 + 0], gcy = tb[b * 4 + 1];
            float gw  = tb[b * 4 + 2], gh  = tb[b * 4 + 3];
            float bx0 = gcx - gw * 0.5f, by0 = gcy - gh * 0.5f;
            float bx1 = gcx + gw * 0.5f, by1 = gcy + gh * 0.5f;

            float ltx = fmaxf(ax0, bx0), lty = fmaxf(ay0, by0);
            float rbx = fminf(ax1, bx1), rby = fminf(ay1, by1);
            float iw = fmaxf(rbx - ltx, 0.0f), ih = fmaxf(rby - lty, 0.0f);
            float inter = iw * ih;
            float areaA = (ax1 - ax0) * (ay1 - ay0);
            float areaB = (bx1 - bx0) * (by1 - by0);
            float uni = areaA + areaB - inter;
            float iou = inter / uni;
            float ccx0 = fminf(ax0, bx0), ccy0 = fminf(ay0, by0);
            float ccx1 = fmaxf(ax1, bx1), ccy1 = fmaxf(ay1, by1);
            float cw = fmaxf(ccx1 - ccx0, 0.0f), ch = fmaxf(ccy1 - ccy0, 0.0f);
            float areaC = cw * ch;
            float giou = iou - (areaC - uni) / areaC;
            sbox[tid] = (double)(1.0f - giou);

            const int cls = tc[b];
            float s = ps[b * (N_CLS * N_ANCH) + cls * N_ANCH + a];
            scorr[tid] = (double)focal0_fast(-s) - (double)focal0_fast(s);
        }
        __syncthreads();
        if (tid == 0) {
            double bs = 0.0, cs = 0.0;
            for (int k = 0; k < TOPK_K; ++k) { bs += sbox[k]; cs += scorr[k]; }
            part[FOCAL_BLOCKS + b]        = bs;   // box partial
            part[FOCAL_BLOCKS + B_SZ + b] = cs;   // corr partial
        }
    }
}

// ---------- kernel 2: single-block finalize (20 KB read) ----------

__global__ __launch_bounds__(256)
void finalize_kernel(const double* __restrict__ part,
                     float* __restrict__ out)
{
    const int tid = threadIdx.x;
    double f = 0.0;
    #pragma unroll
    for (int i = 0; i < FOCAL_BLOCKS / 256; ++i)   // 8 entries each
        f += part[tid + i * 256];
    double bsum = part[FOCAL_BLOCKS + tid];          // 256 entries
    double csum = part[FOCAL_BLOCKS + B_SZ + tid];

    __shared__ double s1[256], s2[256], s3[256];
    s1[tid] = f; s2[tid] = bsum; s3[tid] = csum;
    __syncthreads();
    for (int s = 128; s > 0; s >>= 1) {
        if (tid < s) {
            s1[tid] += s1[tid + s];
            s2[tid] += s2[tid + s];
            s3[tid] += s3[tid + s];
        }
        __syncthreads();
    }
    if (tid == 0) {
        double loss_cls = (s1[0] + s3[0]) / (double)B_SZ;
        double loss_box = s2[0] / (double)(B_SZ * TOPK_K);
        out[0] = (float)(5.0 * loss_box + loss_cls);
        out[1] = (float)loss_box;
        out[2] = (float)loss_cls;
    }
}

// ---------- launch ----------

extern "C" void kernel_launch(void* const* d_in, const int* in_sizes, int n_in,
                              void* d_out, int out_size, void* d_ws, size_t ws_size,
                              hipStream_t stream) {
    const float* pb = (const float*)d_in[0];   // pred_boxes  (256,4,6300)
    const float* ps = (const float*)d_in[1];   // pred_scores (256,10,6300)
    const float* tb = (const float*)d_in[2];   // targets_bbox (256,4)
    const int*   tc = (const int*)d_in[3];     // targets_cls (256,)
    float* out = (float*)d_out;

    double* part = (double*)d_ws;              // 2560 doubles, all written by kernel 1

    fused_work_kernel<<<TOTAL_BLOCKS, 256, 0, stream>>>(pb, ps, tb, tc, part);
    finalize_kernel<<<1, 256, 0, stream>>>(part, out);
}